// Round 1
// baseline (33.773 us; speedup 1.0000x reference)
//
#include <hip/hip_runtime.h>

// SpecAugment: x[B,1,F,T] fp32; zero freq band [f0,f0+f) and time band [t0,t0+t) per batch.
// B=64, F=128, T=3000. Pure memory-bound elementwise masked copy.

constexpr int B_  = 64;
constexpr int F_  = 128;
constexpr int T_  = 3000;
constexpr int T4  = T_ / 4;        // 750 float4 per row (T divisible by 4, no straddle)
constexpr int ROW4 = F_ * T4;      // 96000 float4 per batch sample
constexpr int TOTAL4 = B_ * ROW4;  // 6,144,000 float4 total

__global__ void __launch_bounds__(256)
specaug_kernel(const float4* __restrict__ x,
               const int* __restrict__ t,
               const int* __restrict__ f,
               const int* __restrict__ t0,
               const int* __restrict__ f0,
               float4* __restrict__ out) {
    const int stride = gridDim.x * blockDim.x;
    for (int i = blockIdx.x * blockDim.x + threadIdx.x; i < TOTAL4; i += stride) {
        // decompose: i -> (b, fr, t4); constant divisors -> magic multiply
        const int b   = i / ROW4;
        const int rem = i - b * ROW4;
        const int fr  = rem / T4;
        const int tt  = (rem - fr * T4) * 4;  // time index of component .x

        const int fb = f0[b];
        const int fe = fb + f[b];
        const int tb = t0[b];
        const int te = tb + t[b];

        float4 v = x[i];
        if (fr >= fb && fr < fe) {
            v.x = 0.f; v.y = 0.f; v.z = 0.f; v.w = 0.f;
        } else {
            if (tt + 0 >= tb && tt + 0 < te) v.x = 0.f;
            if (tt + 1 >= tb && tt + 1 < te) v.y = 0.f;
            if (tt + 2 >= tb && tt + 2 < te) v.z = 0.f;
            if (tt + 3 >= tb && tt + 3 < te) v.w = 0.f;
        }
        out[i] = v;
    }
}

extern "C" void kernel_launch(void* const* d_in, const int* in_sizes, int n_in,
                              void* d_out, int out_size, void* d_ws, size_t ws_size,
                              hipStream_t stream) {
    const float4* x = (const float4*)d_in[0];
    const int* t    = (const int*)d_in[1];
    const int* f    = (const int*)d_in[2];
    const int* t0   = (const int*)d_in[3];
    const int* f0   = (const int*)d_in[4];
    float4* out     = (float4*)d_out;

    const int block = 256;
    int grid = (TOTAL4 + block - 1) / block;
    if (grid > 2048) grid = 2048;  // grid-stride the rest (G11)
    specaug_kernel<<<grid, block, 0, stream>>>(x, t, f, t0, f0, out);
}